// Round 12
// baseline (193.241 us; speedup 1.0000x reference)
//
#include <hip/hip_runtime.h>

// Lennard-Jones — R12 ABLATION ROUND. Real pipeline = R11 (66.8us) minus the
// gcursor memset (folded into pack). Appended: two shadow probes (dead scratch
// output, asm-opaqued per-rep indices, x8 inner repeat for top-5 visibility)
// isolating the per-pass type-lookup+energy cost with (A) LDS-staged nibble
// table and (C) global nibble gathers. Decision rules in the analysis.
//
// Inputs: 0 sigma[16,16] 1 delta[16,16] 2 epsilon[16,16] (f32)
//         3 edge_len[E] 4 edge_cutoff[E] (f32)  5 edge_index[2,E] (int32)
//         6 atom_types[N] (int32)         Output: [N,1] f32.

#define THREADS  512
#define EPT      8
#define EPB      (THREADS*EPT)   // 4096
#define STHREADS 256
#define BSHIFT   8
#define BSIZE    256
#define MAXBUCKET 512
#define LDSWORDS  12512          // nibble table cap: 100096 nodes
#define ACCH      8
#define PROBE_REPS 8

__device__ __forceinline__ float lj_energy(float sig, float dlt, float eps,
                                           float len, float cut) {
    const float r  = sig / (len - dlt);
    const float r2 = r * r;
    const float x  = r2 * r2 * r2;               // (sig/(len-dlt))^6
    return 2.0f * eps * (x * x - x) * cut;
}

__device__ __forceinline__ void load_params(const float* __restrict__ sigma,
                                            const float* __restrict__ delta,
                                            const float* __restrict__ epsilon,
                                            float* s_sig, float* s_dlt, float* s_eps,
                                            int t) {
    if (t < 256) {
        const int i  = t >> 4;
        const int j  = t & 15;
        const int lo = min(i, j);
        const int hi = max(i, j);
        const int src = lo * 16 + hi;        // sym = triu(p)+triu(p,1).T
        s_sig[t] = fmaxf(sigma[src],   0.0f);
        s_dlt[t] = fmaxf(delta[src],   0.0f);
        s_eps[t] = fmaxf(epsilon[src], 0.0f);
    }
}

// ---------------- K0: pack atom_types into nibbles + zero gcursor -------------
__global__ __launch_bounds__(STHREADS) void pack_types_kernel(
    const int* __restrict__ at, uint32_t* __restrict__ packed,
    uint32_t* __restrict__ gcursor, int n_nodes)
{
    if (blockIdx.x == 0) {
        gcursor[threadIdx.x] = 0u;
        gcursor[threadIdx.x + 256] = 0u;
    }
    const int w = blockIdx.x * STHREADS + threadIdx.x;
    const int nwords = (n_nodes + 7) >> 3;
    if (w >= nwords) return;
    const int base = w * 8;
    uint32_t v = 0;
    if (base + 8 <= n_nodes) {
        const int4 a = *reinterpret_cast<const int4*>(at + base);
        const int4 b = *reinterpret_cast<const int4*>(at + base + 4);
        v =  (uint32_t)(a.x & 15)        | ((uint32_t)(a.y & 15) << 4)
          | ((uint32_t)(a.z & 15) << 8)  | ((uint32_t)(a.w & 15) << 12)
          | ((uint32_t)(b.x & 15) << 16) | ((uint32_t)(b.y & 15) << 20)
          | ((uint32_t)(b.z & 15) << 24) | ((uint32_t)(b.w & 15) << 28);
    } else {
        for (int k = 0; k < 8; ++k) {
            const int idx = base + k;
            const uint32_t tv = (idx < n_nodes) ? (uint32_t)(at[idx] & 15) : 0u;
            v |= tv << (4 * k);
        }
    }
    packed[w] = v;
}

// ---------------- K1: fused energy + LDS sort + region-reserved scatter -------
__global__ __launch_bounds__(THREADS) void lj_fused(
    const float* __restrict__ sigma,
    const float* __restrict__ delta,
    const float* __restrict__ epsilon,
    const float* __restrict__ edge_len,
    const float* __restrict__ edge_cutoff,
    const int*  __restrict__ edge_index,     // [2,E]
    const uint32_t* __restrict__ packedT,    // [(n+7)/8]
    uint32_t* __restrict__ gcursor,          // [nbucket] region cursors (zeroed)
    uint32_t* __restrict__ pairs,            // [nbucket*REG] regions
    int n_edges, int n_nodes, int nbucket, int REG)
{
    __shared__ float s_sig[256], s_dlt[256], s_eps[256];
    __shared__ __align__(16) uint32_t typeT[LDSWORDS];
    __shared__ uint32_t hist[MAXBUCKET];
    __shared__ uint32_t lbase[MAXBUCKET];
    __shared__ uint32_t gbase[MAXBUCKET];
    __shared__ uint32_t stage[EPB];

    const int t = threadIdx.x;
    load_params(sigma, delta, epsilon, s_sig, s_dlt, s_eps, t);
    hist[t & (MAXBUCKET - 1)] = 0u;

    const int nwords = (n_nodes + 7) >> 3;
    {
        const int nw4 = nwords >> 2;
        const uint4* s4 = reinterpret_cast<const uint4*>(packedT);
        uint4* d4 = reinterpret_cast<uint4*>(typeT);
        for (int i = t; i < nw4; i += THREADS) d4[i] = s4[i];
        for (int i = (nw4 << 2) + t; i < nwords; i += THREADS) typeT[i] = packedT[i];
    }
    __syncthreads();

    #define TYPE_OF(idx) ((typeT[(idx) >> 3] >> (((idx) & 7) << 2)) & 15u)

    const int blk     = blockIdx.x;
    const int blkbase = blk * EPB;
    const int nval    = min(EPB, n_edges - blkbase);

    uint32_t pk[EPT];
    int      bk[EPT];
    #pragma unroll
    for (int i = 0; i < EPT / 4; ++i) {
        const int g = blkbase + i * (THREADS * 4) + t * 4;
        if (g + 3 < n_edges) {
            const int4   ctr = *reinterpret_cast<const int4*>(edge_index + g);
            const int4   oth = *reinterpret_cast<const int4*>(edge_index + n_edges + g);
            const float4 len = *reinterpret_cast<const float4*>(edge_len + g);
            const float4 cut = *reinterpret_cast<const float4*>(edge_cutoff + g);
            const int   c[4] = {ctr.x, ctr.y, ctr.z, ctr.w};
            const int   o[4] = {oth.x, oth.y, oth.z, oth.w};
            const float L[4] = {len.x, len.y, len.z, len.w};
            const float C[4] = {cut.x, cut.y, cut.z, cut.w};
            #pragma unroll
            for (int k = 0; k < 4; ++k) {
                const int fl = (int)((TYPE_OF(c[k]) << 4) | TYPE_OF(o[k]));
                const float e = lj_energy(s_sig[fl], s_dlt[fl], s_eps[fl], L[k], C[k]);
                pk[i*4+k] = (__float_as_uint(e) & ~255u) | (uint32_t)(c[k] & 255);
                bk[i*4+k] = c[k] >> BSHIFT;
                atomicAdd(&hist[bk[i*4+k]], 1u);
            }
        } else {
            #pragma unroll
            for (int k = 0; k < 4; ++k) {
                const int e_idx = g + k;
                if (e_idx < n_edges) {
                    const int ci = edge_index[e_idx];
                    const int oi = edge_index[n_edges + e_idx];
                    const int fl = (int)((TYPE_OF(ci) << 4) | TYPE_OF(oi));
                    const float e = lj_energy(s_sig[fl], s_dlt[fl], s_eps[fl],
                                              edge_len[e_idx], edge_cutoff[e_idx]);
                    pk[i*4+k] = (__float_as_uint(e) & ~255u) | (uint32_t)(ci & 255);
                    bk[i*4+k] = ci >> BSHIFT;
                    atomicAdd(&hist[bk[i*4+k]], 1u);
                } else {
                    bk[i*4+k] = -1;
                }
            }
        }
    }
    __syncthreads();

    if (t < 64) {
        uint32_t v[8]; uint32_t s = 0;
        #pragma unroll
        for (int k = 0; k < 8; ++k) {
            const uint32_t tmp = hist[t * 8 + k];
            v[k] = s; s += tmp;
        }
        uint32_t inc = s;
        #pragma unroll
        for (int off = 1; off < 64; off <<= 1) {
            const uint32_t u = __shfl_up(inc, off, 64);
            if (t >= off) inc += u;
        }
        const uint32_t lane_excl = inc - s;
        #pragma unroll
        for (int k = 0; k < 8; ++k) {
            const uint32_t e = lane_excl + v[k];
            lbase[t * 8 + k] = e;
            hist[t * 8 + k]  = e;
        }
    }
    __syncthreads();

    if (t < nbucket) {
        const uint32_t l0 = lbase[t];
        const uint32_t l1 = (t + 1 < MAXBUCKET) ? lbase[t + 1] : (uint32_t)nval;
        const uint32_t cnt = l1 - l0;
        gbase[t] = (cnt > 0) ? atomicAdd(&gcursor[t], cnt) : 0u;
    }
    #pragma unroll
    for (int j = 0; j < EPT; ++j) {
        if (bk[j] >= 0) {
            const uint32_t r = atomicAdd(&hist[bk[j]], 1u);
            stage[r] = pk[j];
        }
    }
    __syncthreads();

    const int grp = t >> 3;
    const int lig = t & 7;
    for (int b = grp; b < nbucket; b += 64) {
        const uint32_t l0 = lbase[b];
        const uint32_t l1 = (b + 1 < MAXBUCKET) ? lbase[b + 1] : (uint32_t)nval;
        const uint32_t cnt = l1 - l0;
        const uint32_t base = gbase[b];
        const uint32_t avail = (base < (uint32_t)REG)
                             ? min(cnt, (uint32_t)REG - base) : 0u;
        uint32_t* dst = pairs + (size_t)b * REG + base;
        for (uint32_t j = lig; j < avail; j += 8)
            dst[j] = stage[l0 + j];
    }
}

// ---------------- K2: per-(bucket,chunk) region accumulate --------------------
__global__ __launch_bounds__(STHREADS) void lj_accum_kernel(
    const uint32_t* __restrict__ pairs,
    const uint32_t* __restrict__ gcursor,
    float* __restrict__ partial, int REG)
{
    __shared__ float acc[4][BSIZE];
    const int t = threadIdx.x;
    const int b = blockIdx.x;
    const int c = blockIdx.y;

    const uint32_t cnt  = min(gcursor[b], (uint32_t)REG);
    const uint32_t clen = (cnt + ACCH - 1) / ACCH;
    const uint32_t s0   = c * clen;
    const uint32_t s1   = min(cnt, s0 + clen);

    #pragma unroll
    for (int w = 0; w < 4; ++w) acc[w][t] = 0.0f;
    __syncthreads();

    const int wave = t >> 6;
    const uint32_t* reg = pairs + (size_t)b * REG;
    for (uint32_t i = s0 + t; i < s1; i += STHREADS) {
        const uint32_t p = reg[i];
        atomicAdd(&acc[wave][p & 255u], __uint_as_float(p & ~255u));
    }
    __syncthreads();

    partial[(((size_t)b * ACCH + c) << BSHIFT) + t] =
        acc[0][t] + acc[1][t] + acc[2][t] + acc[3][t];
}

// ---------------- K3: reduce chunk-partials -> out ----------------------------
__global__ __launch_bounds__(STHREADS) void lj_reduce_kernel(
    const float* __restrict__ partial, float* __restrict__ out, int n_nodes)
{
    const int n = blockIdx.x * STHREADS + threadIdx.x;
    if (n < n_nodes) {
        const int b = n >> BSHIFT;
        const int i = n & (BSIZE - 1);
        float s = 0.0f;
        #pragma unroll
        for (int c = 0; c < ACCH; ++c)
            s += partial[(((size_t)b * ACCH + c) << BSHIFT) + i];
        out[n] = s;
    }
}

// ================= SHADOW PROBES (dead scratch output; x8 repeat) =============
// Probe A: LDS-staged nibble table lookup + energy (no sort machinery).
__global__ __launch_bounds__(THREADS) void probe_lds(
    const float* __restrict__ sigma,
    const float* __restrict__ delta,
    const float* __restrict__ epsilon,
    const float* __restrict__ edge_len,
    const float* __restrict__ edge_cutoff,
    const int*  __restrict__ edge_index,
    const uint32_t* __restrict__ packedT,
    uint32_t* __restrict__ scratch,
    int n_edges, int n_nodes)
{
    __shared__ float s_sig[256], s_dlt[256], s_eps[256];
    __shared__ __align__(16) uint32_t typeT[LDSWORDS];
    const int t = threadIdx.x;
    load_params(sigma, delta, epsilon, s_sig, s_dlt, s_eps, t);
    const int nwords = (n_nodes + 7) >> 3;
    {
        const int nw4 = nwords >> 2;
        const uint4* s4 = reinterpret_cast<const uint4*>(packedT);
        uint4* d4 = reinterpret_cast<uint4*>(typeT);
        for (int i = t; i < nw4; i += THREADS) d4[i] = s4[i];
        for (int i = (nw4 << 2) + t; i < nwords; i += THREADS) typeT[i] = packedT[i];
    }
    __syncthreads();

    const int blkbase = blockIdx.x * EPB;
    int   c_[EPT], o_[EPT];
    float L_[EPT], C_[EPT];
    #pragma unroll
    for (int i = 0; i < EPT / 4; ++i) {
        const int g = blkbase + i * (THREADS * 4) + t * 4;
        if (g + 3 < n_edges) {
            const int4   ctr = *reinterpret_cast<const int4*>(edge_index + g);
            const int4   oth = *reinterpret_cast<const int4*>(edge_index + n_edges + g);
            const float4 len = *reinterpret_cast<const float4*>(edge_len + g);
            const float4 cut = *reinterpret_cast<const float4*>(edge_cutoff + g);
            c_[i*4+0]=ctr.x; c_[i*4+1]=ctr.y; c_[i*4+2]=ctr.z; c_[i*4+3]=ctr.w;
            o_[i*4+0]=oth.x; o_[i*4+1]=oth.y; o_[i*4+2]=oth.z; o_[i*4+3]=oth.w;
            L_[i*4+0]=len.x; L_[i*4+1]=len.y; L_[i*4+2]=len.z; L_[i*4+3]=len.w;
            C_[i*4+0]=cut.x; C_[i*4+1]=cut.y; C_[i*4+2]=cut.z; C_[i*4+3]=cut.w;
        } else {
            for (int k = 0; k < 4; ++k) {
                const int e = g + k;
                const bool v = (e < n_edges);
                c_[i*4+k] = v ? edge_index[e] : 0;
                o_[i*4+k] = v ? edge_index[n_edges + e] : 0;
                L_[i*4+k] = v ? edge_len[e] : 1.0f;
                C_[i*4+k] = v ? edge_cutoff[e] : 0.0f;
            }
        }
    }

    uint32_t acc = 0;
    for (int rep = 0; rep < PROBE_REPS; ++rep) {
        #pragma unroll
        for (int j = 0; j < EPT; ++j) {
            int ci = c_[j], oi = o_[j];
            asm volatile("" : "+v"(ci), "+v"(oi));   // opaque per rep: force re-lookup
            const int fl = (int)((TYPE_OF(ci) << 4) | TYPE_OF(oi));
            const float e = lj_energy(s_sig[fl], s_dlt[fl], s_eps[fl], L_[j], C_[j]);
            acc ^= __float_as_uint(e);
        }
    }
    scratch[(size_t)blockIdx.x * THREADS + t] = acc;
}

// Probe C: global nibble-table gathers (no LDS table, no staging).
__global__ __launch_bounds__(STHREADS) void probe_g(
    const float* __restrict__ sigma,
    const float* __restrict__ delta,
    const float* __restrict__ epsilon,
    const float* __restrict__ edge_len,
    const float* __restrict__ edge_cutoff,
    const int*  __restrict__ edge_index,
    const uint32_t* __restrict__ packedT,
    uint32_t* __restrict__ scratch,
    int n_edges)
{
    __shared__ float s_sig[256], s_dlt[256], s_eps[256];
    const int t = threadIdx.x;
    load_params(sigma, delta, epsilon, s_sig, s_dlt, s_eps, t);
    __syncthreads();

    #define TYPE_G(idx) ((packedT[(idx) >> 3] >> (((idx) & 7) << 2)) & 15u)

    const int blkbase = blockIdx.x * (STHREADS * EPT);
    int   c_[EPT], o_[EPT];
    float L_[EPT], C_[EPT];
    #pragma unroll
    for (int i = 0; i < EPT / 4; ++i) {
        const int g = blkbase + i * (STHREADS * 4) + t * 4;
        if (g + 3 < n_edges) {
            const int4   ctr = *reinterpret_cast<const int4*>(edge_index + g);
            const int4   oth = *reinterpret_cast<const int4*>(edge_index + n_edges + g);
            const float4 len = *reinterpret_cast<const float4*>(edge_len + g);
            const float4 cut = *reinterpret_cast<const float4*>(edge_cutoff + g);
            c_[i*4+0]=ctr.x; c_[i*4+1]=ctr.y; c_[i*4+2]=ctr.z; c_[i*4+3]=ctr.w;
            o_[i*4+0]=oth.x; o_[i*4+1]=oth.y; o_[i*4+2]=oth.z; o_[i*4+3]=oth.w;
            L_[i*4+0]=len.x; L_[i*4+1]=len.y; L_[i*4+2]=len.z; L_[i*4+3]=len.w;
            C_[i*4+0]=cut.x; C_[i*4+1]=cut.y; C_[i*4+2]=cut.z; C_[i*4+3]=cut.w;
        } else {
            for (int k = 0; k < 4; ++k) {
                const int e = g + k;
                const bool v = (e < n_edges);
                c_[i*4+k] = v ? edge_index[e] : 0;
                o_[i*4+k] = v ? edge_index[n_edges + e] : 0;
                L_[i*4+k] = v ? edge_len[e] : 1.0f;
                C_[i*4+k] = v ? edge_cutoff[e] : 0.0f;
            }
        }
    }

    uint32_t acc = 0;
    for (int rep = 0; rep < PROBE_REPS; ++rep) {
        #pragma unroll
        for (int j = 0; j < EPT; ++j) {
            int ci = c_[j], oi = o_[j];
            asm volatile("" : "+v"(ci), "+v"(oi));
            const int fl = (int)((TYPE_G(ci) << 4) | TYPE_G(oi));
            const float e = lj_energy(s_sig[fl], s_dlt[fl], s_eps[fl], L_[j], C_[j]);
            acc ^= __float_as_uint(e);
        }
    }
    scratch[(size_t)blockIdx.x * STHREADS + t] = acc;
}

// ---------------- fallback: direct device-scope atomics -----------------------
__global__ __launch_bounds__(STHREADS) void lj_scatter_direct(
    const float* __restrict__ sigma,
    const float* __restrict__ delta,
    const float* __restrict__ epsilon,
    const float* __restrict__ edge_len,
    const float* __restrict__ edge_cutoff,
    const int*  __restrict__ edge_index,
    const int*  __restrict__ atom_types,
    float* __restrict__ out,
    int n_edges)
{
    __shared__ float s_sig[256], s_dlt[256], s_eps[256];
    const int t = threadIdx.x;
    load_params(sigma, delta, epsilon, s_sig, s_dlt, s_eps, t);
    __syncthreads();

    const int base = (blockIdx.x * STHREADS + t) * 4;
    if (base >= n_edges) return;
    const int lim = min(base + 4, n_edges);
    for (int e = base; e < lim; ++e) {
        const int ci = edge_index[e];
        const int oi = edge_index[n_edges + e];
        const int fl = (atom_types[ci] << 4) | atom_types[oi];
        const float en = lj_energy(s_sig[fl], s_dlt[fl], s_eps[fl],
                                   edge_len[e], edge_cutoff[e]);
        atomicAdd(out + ci, en);
    }
}

static inline size_t align16(size_t x) { return (x + 15) & ~(size_t)15; }

extern "C" void kernel_launch(void* const* d_in, const int* in_sizes, int n_in,
                              void* d_out, int out_size, void* d_ws, size_t ws_size,
                              hipStream_t stream) {
    const float* sigma       = (const float*)d_in[0];
    const float* delta       = (const float*)d_in[1];
    const float* epsilon     = (const float*)d_in[2];
    const float* edge_len    = (const float*)d_in[3];
    const float* edge_cutoff = (const float*)d_in[4];
    const int*   edge_index  = (const int*)d_in[5];
    const int*   atom_types  = (const int*)d_in[6];
    float*       out         = (float*)d_out;

    const int n_edges = in_sizes[3];
    const int n_nodes = in_sizes[6];

    const int nblk    = (n_edges + EPB - 1) / EPB;
    const int nbucket = (n_nodes + BSIZE - 1) / BSIZE;
    const int nwords  = (n_nodes + 7) >> 3;

    int REG = 2 * (n_edges / (nbucket > 0 ? nbucket : 1));
    REG = ((REG + 1023) / 1024) * 1024;
    if (REG < 2048) REG = 2048;

    const size_t gcur_bytes   = align16((size_t)MAXBUCKET * sizeof(uint32_t));
    const size_t packed_bytes = align16((size_t)nwords * sizeof(uint32_t));
    const size_t pairs_bytes  = align16((size_t)nbucket * REG * sizeof(uint32_t));
    const size_t part_bytes   = align16((size_t)nbucket * ACCH * BSIZE * sizeof(float));
    const size_t need = gcur_bytes + packed_bytes + pairs_bytes + part_bytes;

    const int nblkC = (n_edges + STHREADS * EPT - 1) / (STHREADS * EPT);
    const size_t scrA_bytes = align16((size_t)nblk * THREADS * sizeof(uint32_t));
    const size_t scrC_bytes = align16((size_t)nblkC * STHREADS * sizeof(uint32_t));
    const bool do_probes = (ws_size >= need + scrA_bytes + scrC_bytes);

    if (nbucket <= MAXBUCKET && nwords <= LDSWORDS && ws_size >= need) {
        char* p = (char*)d_ws;
        uint32_t* gcursor = (uint32_t*)p;  p += gcur_bytes;
        uint32_t* packed  = (uint32_t*)p;  p += packed_bytes;
        uint32_t* pairs   = (uint32_t*)p;  p += pairs_bytes;
        float*    partial = (float*)p;     p += part_bytes;
        uint32_t* scrA    = (uint32_t*)p;  p += scrA_bytes;
        uint32_t* scrC    = (uint32_t*)p;

        const int pgrid = (nwords + STHREADS - 1) / STHREADS;
        pack_types_kernel<<<pgrid, STHREADS, 0, stream>>>(
            atom_types, packed, gcursor, n_nodes);

        lj_fused<<<nblk, THREADS, 0, stream>>>(
            sigma, delta, epsilon, edge_len, edge_cutoff,
            edge_index, packed, gcursor, pairs, n_edges, n_nodes, nbucket, REG);

        lj_accum_kernel<<<dim3(nbucket, ACCH), STHREADS, 0, stream>>>(
            pairs, gcursor, partial, REG);

        const int rgrid = (n_nodes + STHREADS - 1) / STHREADS;
        lj_reduce_kernel<<<rgrid, STHREADS, 0, stream>>>(partial, out, n_nodes);

        if (do_probes) {
            probe_lds<<<nblk, THREADS, 0, stream>>>(
                sigma, delta, epsilon, edge_len, edge_cutoff,
                edge_index, packed, scrA, n_edges, n_nodes);
            probe_g<<<nblkC, STHREADS, 0, stream>>>(
                sigma, delta, epsilon, edge_len, edge_cutoff,
                edge_index, packed, scrC, n_edges);
        }
    } else {
        hipMemsetAsync(d_out, 0, (size_t)out_size * sizeof(float), stream);
        const int grid = (n_edges + STHREADS * 4 - 1) / (STHREADS * 4);
        lj_scatter_direct<<<grid, STHREADS, 0, stream>>>(
            sigma, delta, epsilon, edge_len, edge_cutoff,
            edge_index, atom_types, out, n_edges);
    }
}

// Round 13
// 68.958 us; speedup vs baseline: 2.8023x; 2.8023x over previous
//
#include <hip/hip_runtime.h>

// Lennard-Jones per-edge energy + segment-sum — fused single-pass binning.
//
// R12 ablation: LDS-table lookup+energy = ~2us/pass (cheap!); global nibble
// lookup = ~11us/pass; => R11 fused's 41us was the 75.7KB LDS footprint
// (2 blocks/CU) latency-exposing the sort phases, not the lookups.
// R13: drop the 50KB LDS typeT from the fused kernel; lookups hit the global
// 50KB nibble table (L2-resident, overlappable at 4 blocks/CU = full wave cap).
// Region reservation atomics halved via u64 bucket-pair packed atomicAdd.
//
// Inputs: 0 sigma[16,16] 1 delta[16,16] 2 epsilon[16,16] (f32)
//         3 edge_len[E] 4 edge_cutoff[E] (f32)  5 edge_index[2,E] (int32)
//         6 atom_types[N] (int32)         Output: [N,1] f32.

#define THREADS  512
#define EPT      8
#define EPB      (THREADS*EPT)   // 4096
#define STHREADS 256
#define BSHIFT   8
#define BSIZE    256
#define MAXBUCKET 512
#define ACCH      8              // accum chunks per bucket

__device__ __forceinline__ float lj_energy(float sig, float dlt, float eps,
                                           float len, float cut) {
    const float r  = sig / (len - dlt);
    const float r2 = r * r;
    const float x  = r2 * r2 * r2;               // (sig/(len-dlt))^6
    return 2.0f * eps * (x * x - x) * cut;
}

__device__ __forceinline__ void load_params(const float* __restrict__ sigma,
                                            const float* __restrict__ delta,
                                            const float* __restrict__ epsilon,
                                            float* s_sig, float* s_dlt, float* s_eps,
                                            int t) {
    if (t < 256) {
        const int i  = t >> 4;
        const int j  = t & 15;
        const int lo = min(i, j);
        const int hi = max(i, j);
        const int src = lo * 16 + hi;        // sym = triu(p)+triu(p,1).T
        s_sig[t] = fmaxf(sigma[src],   0.0f);
        s_dlt[t] = fmaxf(delta[src],   0.0f);
        s_eps[t] = fmaxf(epsilon[src], 0.0f);
    }
}

// ---------------- K0: pack atom_types into nibbles + zero gcursor -------------
__global__ __launch_bounds__(STHREADS) void pack_types_kernel(
    const int* __restrict__ at, uint32_t* __restrict__ packed,
    uint32_t* __restrict__ gcursor, int n_nodes)
{
    if (blockIdx.x == 0) {
        gcursor[threadIdx.x] = 0u;
        gcursor[threadIdx.x + 256] = 0u;
    }
    const int w = blockIdx.x * STHREADS + threadIdx.x;
    const int nwords = (n_nodes + 7) >> 3;
    if (w >= nwords) return;
    const int base = w * 8;
    uint32_t v = 0;
    if (base + 8 <= n_nodes) {
        const int4 a = *reinterpret_cast<const int4*>(at + base);
        const int4 b = *reinterpret_cast<const int4*>(at + base + 4);
        v =  (uint32_t)(a.x & 15)        | ((uint32_t)(a.y & 15) << 4)
          | ((uint32_t)(a.z & 15) << 8)  | ((uint32_t)(a.w & 15) << 12)
          | ((uint32_t)(b.x & 15) << 16) | ((uint32_t)(b.y & 15) << 20)
          | ((uint32_t)(b.z & 15) << 24) | ((uint32_t)(b.w & 15) << 28);
    } else {
        for (int k = 0; k < 8; ++k) {
            const int idx = base + k;
            const uint32_t tv = (idx < n_nodes) ? (uint32_t)(at[idx] & 15) : 0u;
            v |= tv << (4 * k);
        }
    }
    packed[w] = v;
}

// ---------------- K1: fused energy + LDS sort + region-reserved scatter -------
__global__ __launch_bounds__(THREADS) void lj_fused(
    const float* __restrict__ sigma,
    const float* __restrict__ delta,
    const float* __restrict__ epsilon,
    const float* __restrict__ edge_len,
    const float* __restrict__ edge_cutoff,
    const int*  __restrict__ edge_index,     // [2,E]
    const uint32_t* __restrict__ packedT,    // [(n+7)/8] global nibble table
    uint32_t* __restrict__ gcursor,          // [MAXBUCKET] cursors (u64-pair packed)
    uint32_t* __restrict__ pairs,            // [nbucket*REG] regions
    int n_edges, int nbucket, int REG)
{
    __shared__ float s_sig[256], s_dlt[256], s_eps[256];
    __shared__ uint32_t hist[MAXBUCKET];     // counts -> cursor
    __shared__ uint32_t lbase[MAXBUCKET];    // local exclusive base
    __shared__ uint32_t gbase[MAXBUCKET];    // reserved global base (per block)
    __shared__ uint32_t stage[EPB];          // 16KB sorted stage

    const int t = threadIdx.x;
    load_params(sigma, delta, epsilon, s_sig, s_dlt, s_eps, t);
    hist[t & (MAXBUCKET - 1)] = 0u;
    __syncthreads();

    #define TYPE_G(idx) ((packedT[(idx) >> 3] >> (((idx) & 7) << 2)) & 15u)

    const int blk     = blockIdx.x;
    const int blkbase = blk * EPB;
    const int nval    = min(EPB, n_edges - blkbase);

    // process 8 edges/thread: global nibble lookups + energy + pack + histogram
    uint32_t pk[EPT];
    int      bk[EPT];
    #pragma unroll
    for (int i = 0; i < EPT / 4; ++i) {
        const int g = blkbase + i * (THREADS * 4) + t * 4;
        if (g + 3 < n_edges) {
            const int4   ctr = *reinterpret_cast<const int4*>(edge_index + g);
            const int4   oth = *reinterpret_cast<const int4*>(edge_index + n_edges + g);
            const float4 len = *reinterpret_cast<const float4*>(edge_len + g);
            const float4 cut = *reinterpret_cast<const float4*>(edge_cutoff + g);
            const int   c[4] = {ctr.x, ctr.y, ctr.z, ctr.w};
            const int   o[4] = {oth.x, oth.y, oth.z, oth.w};
            const float L[4] = {len.x, len.y, len.z, len.w};
            const float C[4] = {cut.x, cut.y, cut.z, cut.w};
            #pragma unroll
            for (int k = 0; k < 4; ++k) {
                const int fl = (int)((TYPE_G(c[k]) << 4) | TYPE_G(o[k]));
                const float e = lj_energy(s_sig[fl], s_dlt[fl], s_eps[fl], L[k], C[k]);
                pk[i*4+k] = (__float_as_uint(e) & ~255u) | (uint32_t)(c[k] & 255);
                bk[i*4+k] = c[k] >> BSHIFT;
                atomicAdd(&hist[bk[i*4+k]], 1u);
            }
        } else {
            #pragma unroll
            for (int k = 0; k < 4; ++k) {
                const int e_idx = g + k;
                if (e_idx < n_edges) {
                    const int ci = edge_index[e_idx];
                    const int oi = edge_index[n_edges + e_idx];
                    const int fl = (int)((TYPE_G(ci) << 4) | TYPE_G(oi));
                    const float e = lj_energy(s_sig[fl], s_dlt[fl], s_eps[fl],
                                              edge_len[e_idx], edge_cutoff[e_idx]);
                    pk[i*4+k] = (__float_as_uint(e) & ~255u) | (uint32_t)(ci & 255);
                    bk[i*4+k] = ci >> BSHIFT;
                    atomicAdd(&hist[bk[i*4+k]], 1u);
                } else {
                    bk[i*4+k] = -1;
                }
            }
        }
    }
    __syncthreads();

    // wave-0 in-register exclusive scan of hist[0..511] -> lbase + cursor
    if (t < 64) {
        uint32_t v[8]; uint32_t s = 0;
        #pragma unroll
        for (int k = 0; k < 8; ++k) {
            const uint32_t tmp = hist[t * 8 + k];
            v[k] = s; s += tmp;
        }
        uint32_t inc = s;
        #pragma unroll
        for (int off = 1; off < 64; off <<= 1) {
            const uint32_t u = __shfl_up(inc, off, 64);
            if (t >= off) inc += u;
        }
        const uint32_t lane_excl = inc - s;
        #pragma unroll
        for (int k = 0; k < 8; ++k) {
            const uint32_t e = lane_excl + v[k];
            lbase[t * 8 + k] = e;
            hist[t * 8 + k]  = e;        // cursor
        }
    }
    __syncthreads();

    // reserve region slots: ONE u64 atomic per bucket PAIR (halved atomic count).
    // little-endian: lo half = bucket 2t (gcursor[2t]), hi half = bucket 2t+1.
    if (t < MAXBUCKET / 2) {
        const int b0 = 2 * t, b1 = 2 * t + 1;
        const uint32_t l0 = lbase[b0];
        const uint32_t l1 = lbase[b1];
        const uint32_t l2 = (b1 + 1 < MAXBUCKET) ? lbase[b1 + 1] : (uint32_t)nval;
        const uint32_t cnt0 = l1 - l0;
        const uint32_t cnt1 = l2 - l1;
        if ((cnt0 | cnt1) != 0u) {
            unsigned long long* g64 =
                reinterpret_cast<unsigned long long*>(gcursor) + t;
            const unsigned long long add =
                (unsigned long long)cnt0 | ((unsigned long long)cnt1 << 32);
            const unsigned long long old = atomicAdd(g64, add);
            gbase[b0] = (uint32_t)old;
            gbase[b1] = (uint32_t)(old >> 32);
        }
    }
    // rank-scatter into the LDS stage (overlaps the reservation)
    #pragma unroll
    for (int j = 0; j < EPT; ++j) {
        if (bk[j] >= 0) {
            const uint32_t r = atomicAdd(&hist[bk[j]], 1u);
            stage[r] = pk[j];
        }
    }
    __syncthreads();

    // run-coalesced copy-out into reserved region slots
    const int grp = t >> 3;              // 64 groups of 8 lanes
    const int lig = t & 7;
    for (int b = grp; b < nbucket; b += 64) {
        const uint32_t l0 = lbase[b];
        const uint32_t l1 = (b + 1 < MAXBUCKET) ? lbase[b + 1] : (uint32_t)nval;
        const uint32_t cnt = l1 - l0;
        const uint32_t base = gbase[b];
        const uint32_t avail = (base < (uint32_t)REG)
                             ? min(cnt, (uint32_t)REG - base) : 0u;  // overflow guard
        uint32_t* dst = pairs + (size_t)b * REG + base;
        for (uint32_t j = lig; j < avail; j += 8)
            dst[j] = stage[l0 + j];
    }
}

// ---------------- K2: per-(bucket,chunk) region accumulate --------------------
__global__ __launch_bounds__(STHREADS) void lj_accum_kernel(
    const uint32_t* __restrict__ pairs,
    const uint32_t* __restrict__ gcursor,
    float* __restrict__ partial,             // [nbucket*ACCH*256]
    int REG)
{
    __shared__ float acc[4][BSIZE];
    const int t = threadIdx.x;
    const int b = blockIdx.x;
    const int c = blockIdx.y;

    const uint32_t cnt  = min(gcursor[b], (uint32_t)REG);
    const uint32_t clen = (cnt + ACCH - 1) / ACCH;
    const uint32_t s0   = c * clen;
    const uint32_t s1   = min(cnt, s0 + clen);

    #pragma unroll
    for (int w = 0; w < 4; ++w) acc[w][t] = 0.0f;
    __syncthreads();

    const int wave = t >> 6;
    const uint32_t* reg = pairs + (size_t)b * REG;
    for (uint32_t i = s0 + t; i < s1; i += STHREADS) {
        const uint32_t p = reg[i];
        atomicAdd(&acc[wave][p & 255u], __uint_as_float(p & ~255u));
    }
    __syncthreads();

    partial[(((size_t)b * ACCH + c) << BSHIFT) + t] =
        acc[0][t] + acc[1][t] + acc[2][t] + acc[3][t];
}

// ---------------- K3: reduce ACCH chunk-partials -> out -----------------------
__global__ __launch_bounds__(STHREADS) void lj_reduce_kernel(
    const float* __restrict__ partial, float* __restrict__ out, int n_nodes)
{
    const int n = blockIdx.x * STHREADS + threadIdx.x;
    if (n < n_nodes) {
        const int b = n >> BSHIFT;
        const int i = n & (BSIZE - 1);
        float s = 0.0f;
        #pragma unroll
        for (int c = 0; c < ACCH; ++c)
            s += partial[(((size_t)b * ACCH + c) << BSHIFT) + i];
        out[n] = s;
    }
}

// ---------------- fallback: direct device-scope atomics -----------------------
__global__ __launch_bounds__(STHREADS) void lj_scatter_direct(
    const float* __restrict__ sigma,
    const float* __restrict__ delta,
    const float* __restrict__ epsilon,
    const float* __restrict__ edge_len,
    const float* __restrict__ edge_cutoff,
    const int*  __restrict__ edge_index,
    const int*  __restrict__ atom_types,
    float* __restrict__ out,
    int n_edges)
{
    __shared__ float s_sig[256], s_dlt[256], s_eps[256];
    const int t = threadIdx.x;
    load_params(sigma, delta, epsilon, s_sig, s_dlt, s_eps, t);
    __syncthreads();

    const int base = (blockIdx.x * STHREADS + t) * 4;
    if (base >= n_edges) return;
    const int lim = min(base + 4, n_edges);
    for (int e = base; e < lim; ++e) {
        const int ci = edge_index[e];
        const int oi = edge_index[n_edges + e];
        const int fl = (atom_types[ci] << 4) | atom_types[oi];
        const float en = lj_energy(s_sig[fl], s_dlt[fl], s_eps[fl],
                                   edge_len[e], edge_cutoff[e]);
        atomicAdd(out + ci, en);
    }
}

static inline size_t align16(size_t x) { return (x + 15) & ~(size_t)15; }

extern "C" void kernel_launch(void* const* d_in, const int* in_sizes, int n_in,
                              void* d_out, int out_size, void* d_ws, size_t ws_size,
                              hipStream_t stream) {
    const float* sigma       = (const float*)d_in[0];
    const float* delta       = (const float*)d_in[1];
    const float* epsilon     = (const float*)d_in[2];
    const float* edge_len    = (const float*)d_in[3];
    const float* edge_cutoff = (const float*)d_in[4];
    const int*   edge_index  = (const int*)d_in[5];
    const int*   atom_types  = (const int*)d_in[6];
    float*       out         = (float*)d_out;

    const int n_edges = in_sizes[3];
    const int n_nodes = in_sizes[6];

    const int nblk    = (n_edges + EPB - 1) / EPB;
    const int nbucket = (n_nodes + BSIZE - 1) / BSIZE;
    const int nwords  = (n_nodes + 7) >> 3;

    // region size: 2x mean bucket load, rounded up to 1K (overflow-guarded)
    int REG = 2 * (n_edges / (nbucket > 0 ? nbucket : 1));
    REG = ((REG + 1023) / 1024) * 1024;
    if (REG < 2048) REG = 2048;

    const size_t gcur_bytes   = align16((size_t)MAXBUCKET * sizeof(uint32_t));
    const size_t packed_bytes = align16((size_t)nwords * sizeof(uint32_t));
    const size_t pairs_bytes  = align16((size_t)nbucket * REG * sizeof(uint32_t));
    const size_t part_bytes   = align16((size_t)nbucket * ACCH * BSIZE * sizeof(float));
    const size_t need = gcur_bytes + packed_bytes + pairs_bytes + part_bytes;

    if (nbucket <= MAXBUCKET && ws_size >= need) {
        char* p = (char*)d_ws;
        uint32_t* gcursor = (uint32_t*)p;  p += gcur_bytes;
        uint32_t* packed  = (uint32_t*)p;  p += packed_bytes;
        uint32_t* pairs   = (uint32_t*)p;  p += pairs_bytes;
        float*    partial = (float*)p;

        const int pgrid = (nwords + STHREADS - 1) / STHREADS;
        pack_types_kernel<<<pgrid, STHREADS, 0, stream>>>(
            atom_types, packed, gcursor, n_nodes);

        lj_fused<<<nblk, THREADS, 0, stream>>>(
            sigma, delta, epsilon, edge_len, edge_cutoff,
            edge_index, packed, gcursor, pairs, n_edges, nbucket, REG);

        lj_accum_kernel<<<dim3(nbucket, ACCH), STHREADS, 0, stream>>>(
            pairs, gcursor, partial, REG);

        const int rgrid = (n_nodes + STHREADS - 1) / STHREADS;
        lj_reduce_kernel<<<rgrid, STHREADS, 0, stream>>>(partial, out, n_nodes);
    } else {
        hipMemsetAsync(d_out, 0, (size_t)out_size * sizeof(float), stream);
        const int grid = (n_edges + STHREADS * 4 - 1) / (STHREADS * 4);
        lj_scatter_direct<<<grid, STHREADS, 0, stream>>>(
            sigma, delta, epsilon, edge_len, edge_cutoff,
            edge_index, atom_types, out, n_edges);
    }
}

// Round 14
// 66.413 us; speedup vs baseline: 2.9097x; 1.0383x over previous
//
#include <hip/hip_runtime.h>

// Lennard-Jones per-edge energy + segment-sum — fused single-pass binning.
//
// R13 evidence: global-lookup swap regressed despite higher occupancy ->
// sort-phase cost is not occupancy-latency; LDS table restored. R12 probes:
// front-end ~12us => sort machinery+writes ~29us. R14 attacks the two top
// suspects vs R11 (clean A/B, same front-end): buckets 256->512 nodes
// (node>>9): reservation atomics 306K -> 38K u64-paired (~8x), copy-out run
// length 2x (~84B segments), hist/scan halved. 9-bit node packing (absmax
// ~32 vs threshold 152).
//
// Inputs: 0 sigma[16,16] 1 delta[16,16] 2 epsilon[16,16] (f32)
//         3 edge_len[E] 4 edge_cutoff[E] (f32)  5 edge_index[2,E] (int32)
//         6 atom_types[N] (int32)         Output: [N,1] f32.

#define THREADS  512
#define EPT      8
#define EPB      (THREADS*EPT)   // 4096
#define STHREADS 256
#define BSHIFT   9
#define BSIZE    512             // nodes per bucket
#define MAXB2    256             // LDS bucket-array size (nbucket <= 256)
#define NMASK    511u
#define LDSWORDS 12544           // nibble table cap: 100352 nodes
#define ACCH     4               // accum chunks per bucket

__device__ __forceinline__ float lj_energy(float sig, float dlt, float eps,
                                           float len, float cut) {
    const float r  = sig / (len - dlt);
    const float r2 = r * r;
    const float x  = r2 * r2 * r2;               // (sig/(len-dlt))^6
    return 2.0f * eps * (x * x - x) * cut;
}

__device__ __forceinline__ void load_params(const float* __restrict__ sigma,
                                            const float* __restrict__ delta,
                                            const float* __restrict__ epsilon,
                                            float* s_sig, float* s_dlt, float* s_eps,
                                            int t) {
    if (t < 256) {
        const int i  = t >> 4;
        const int j  = t & 15;
        const int lo = min(i, j);
        const int hi = max(i, j);
        const int src = lo * 16 + hi;        // sym = triu(p)+triu(p,1).T
        s_sig[t] = fmaxf(sigma[src],   0.0f);
        s_dlt[t] = fmaxf(delta[src],   0.0f);
        s_eps[t] = fmaxf(epsilon[src], 0.0f);
    }
}

// ---------------- K0: pack atom_types into nibbles + zero gcursor -------------
__global__ __launch_bounds__(STHREADS) void pack_types_kernel(
    const int* __restrict__ at, uint32_t* __restrict__ packed,
    uint32_t* __restrict__ gcursor, int n_nodes)
{
    if (blockIdx.x == 0) gcursor[threadIdx.x] = 0u;   // 256 entries
    const int w = blockIdx.x * STHREADS + threadIdx.x;
    const int nwords = (n_nodes + 7) >> 3;
    if (w >= nwords) return;
    const int base = w * 8;
    uint32_t v = 0;
    if (base + 8 <= n_nodes) {
        const int4 a = *reinterpret_cast<const int4*>(at + base);
        const int4 b = *reinterpret_cast<const int4*>(at + base + 4);
        v =  (uint32_t)(a.x & 15)        | ((uint32_t)(a.y & 15) << 4)
          | ((uint32_t)(a.z & 15) << 8)  | ((uint32_t)(a.w & 15) << 12)
          | ((uint32_t)(b.x & 15) << 16) | ((uint32_t)(b.y & 15) << 20)
          | ((uint32_t)(b.z & 15) << 24) | ((uint32_t)(b.w & 15) << 28);
    } else {
        for (int k = 0; k < 8; ++k) {
            const int idx = base + k;
            const uint32_t tv = (idx < n_nodes) ? (uint32_t)(at[idx] & 15) : 0u;
            v |= tv << (4 * k);
        }
    }
    packed[w] = v;
}

// ---------------- K1: fused energy + LDS sort + region-reserved scatter -------
__global__ __launch_bounds__(THREADS) void lj_fused(
    const float* __restrict__ sigma,
    const float* __restrict__ delta,
    const float* __restrict__ epsilon,
    const float* __restrict__ edge_len,
    const float* __restrict__ edge_cutoff,
    const int*  __restrict__ edge_index,     // [2,E]
    const uint32_t* __restrict__ packedT,    // [(n+7)/8]
    uint32_t* __restrict__ gcursor,          // [MAXB2] cursors (u64-pair packed)
    uint32_t* __restrict__ pairs,            // [nbucket*REG] regions
    int n_edges, int n_nodes, int nbucket, int REG)
{
    __shared__ float s_sig[256], s_dlt[256], s_eps[256];
    __shared__ __align__(16) uint32_t typeT[LDSWORDS];  // 50KB nibble table
    __shared__ uint32_t hist[MAXB2];         // counts -> cursor
    __shared__ uint32_t lbase[MAXB2];        // local exclusive base
    __shared__ uint32_t gbase[MAXB2];        // reserved global base (per block)
    __shared__ uint32_t stage[EPB];          // 16KB sorted stage

    const int t = threadIdx.x;
    load_params(sigma, delta, epsilon, s_sig, s_dlt, s_eps, t);
    if (t < MAXB2) hist[t] = 0u;

    // stage nibble table into LDS
    const int nwords = (n_nodes + 7) >> 3;
    {
        const int nw4 = nwords >> 2;
        const uint4* s4 = reinterpret_cast<const uint4*>(packedT);
        uint4* d4 = reinterpret_cast<uint4*>(typeT);
        for (int i = t; i < nw4; i += THREADS) d4[i] = s4[i];
        for (int i = (nw4 << 2) + t; i < nwords; i += THREADS) typeT[i] = packedT[i];
    }
    __syncthreads();

    #define TYPE_OF(idx) ((typeT[(idx) >> 3] >> (((idx) & 7) << 2)) & 15u)

    const int blk     = blockIdx.x;
    const int blkbase = blk * EPB;
    const int nval    = min(EPB, n_edges - blkbase);

    // 8 edges/thread: lookup + energy + pack + histogram
    uint32_t pk[EPT];
    int      bk[EPT];
    #pragma unroll
    for (int i = 0; i < EPT / 4; ++i) {
        const int g = blkbase + i * (THREADS * 4) + t * 4;
        if (g + 3 < n_edges) {
            const int4   ctr = *reinterpret_cast<const int4*>(edge_index + g);
            const int4   oth = *reinterpret_cast<const int4*>(edge_index + n_edges + g);
            const float4 len = *reinterpret_cast<const float4*>(edge_len + g);
            const float4 cut = *reinterpret_cast<const float4*>(edge_cutoff + g);
            const int   c[4] = {ctr.x, ctr.y, ctr.z, ctr.w};
            const int   o[4] = {oth.x, oth.y, oth.z, oth.w};
            const float L[4] = {len.x, len.y, len.z, len.w};
            const float C[4] = {cut.x, cut.y, cut.z, cut.w};
            #pragma unroll
            for (int k = 0; k < 4; ++k) {
                const int fl = (int)((TYPE_OF(c[k]) << 4) | TYPE_OF(o[k]));
                const float e = lj_energy(s_sig[fl], s_dlt[fl], s_eps[fl], L[k], C[k]);
                pk[i*4+k] = (__float_as_uint(e) & ~NMASK) | (uint32_t)(c[k] & NMASK);
                bk[i*4+k] = c[k] >> BSHIFT;
                atomicAdd(&hist[bk[i*4+k]], 1u);
            }
        } else {
            #pragma unroll
            for (int k = 0; k < 4; ++k) {
                const int e_idx = g + k;
                if (e_idx < n_edges) {
                    const int ci = edge_index[e_idx];
                    const int oi = edge_index[n_edges + e_idx];
                    const int fl = (int)((TYPE_OF(ci) << 4) | TYPE_OF(oi));
                    const float e = lj_energy(s_sig[fl], s_dlt[fl], s_eps[fl],
                                              edge_len[e_idx], edge_cutoff[e_idx]);
                    pk[i*4+k] = (__float_as_uint(e) & ~NMASK) | (uint32_t)(ci & NMASK);
                    bk[i*4+k] = ci >> BSHIFT;
                    atomicAdd(&hist[bk[i*4+k]], 1u);
                } else {
                    bk[i*4+k] = -1;
                }
            }
        }
    }
    __syncthreads();

    // wave-0 in-register exclusive scan of hist[0..255] (4 entries/lane)
    if (t < 64) {
        uint32_t v[4]; uint32_t s = 0;
        #pragma unroll
        for (int k = 0; k < 4; ++k) {
            const uint32_t tmp = hist[t * 4 + k];
            v[k] = s; s += tmp;
        }
        uint32_t inc = s;
        #pragma unroll
        for (int off = 1; off < 64; off <<= 1) {
            const uint32_t u = __shfl_up(inc, off, 64);
            if (t >= off) inc += u;
        }
        const uint32_t lane_excl = inc - s;
        #pragma unroll
        for (int k = 0; k < 4; ++k) {
            const uint32_t e = lane_excl + v[k];
            lbase[t * 4 + k] = e;
            hist[t * 4 + k]  = e;        // cursor
        }
    }
    __syncthreads();

    // reserve region slots: ONE u64 atomic per bucket PAIR (~49/block)
    if (t < MAXB2 / 2) {
        const int b0 = 2 * t, b1 = 2 * t + 1;
        const uint32_t l0 = lbase[b0];
        const uint32_t l1 = lbase[b1];
        const uint32_t l2 = (b1 + 1 < MAXB2) ? lbase[b1 + 1] : (uint32_t)nval;
        const uint32_t cnt0 = l1 - l0;
        const uint32_t cnt1 = l2 - l1;
        if ((cnt0 | cnt1) != 0u) {
            unsigned long long* g64 =
                reinterpret_cast<unsigned long long*>(gcursor) + t;
            const unsigned long long add =
                (unsigned long long)cnt0 | ((unsigned long long)cnt1 << 32);
            const unsigned long long old = atomicAdd(g64, add);
            gbase[b0] = (uint32_t)old;
            gbase[b1] = (uint32_t)(old >> 32);
        }
    }
    // rank-scatter into the LDS stage (overlaps the reservation)
    #pragma unroll
    for (int j = 0; j < EPT; ++j) {
        if (bk[j] >= 0) {
            const uint32_t r = atomicAdd(&hist[bk[j]], 1u);
            stage[r] = pk[j];
        }
    }
    __syncthreads();

    // run-coalesced copy-out into reserved region slots
    const int grp = t >> 3;              // 64 groups of 8 lanes
    const int lig = t & 7;
    for (int b = grp; b < nbucket; b += 64) {
        const uint32_t l0 = lbase[b];
        const uint32_t l1 = (b + 1 < MAXB2) ? lbase[b + 1] : (uint32_t)nval;
        const uint32_t cnt = l1 - l0;
        const uint32_t base = gbase[b];
        const uint32_t avail = (base < (uint32_t)REG)
                             ? min(cnt, (uint32_t)REG - base) : 0u;  // overflow guard
        uint32_t* dst = pairs + (size_t)b * REG + base;
        for (uint32_t j = lig; j < avail; j += 8)
            dst[j] = stage[l0 + j];
    }
}

// ---------------- K2: per-(bucket,chunk) region accumulate --------------------
__global__ __launch_bounds__(STHREADS) void lj_accum_kernel(
    const uint32_t* __restrict__ pairs,
    const uint32_t* __restrict__ gcursor,
    float* __restrict__ partial,             // [nbucket*ACCH*BSIZE]
    int REG)
{
    __shared__ float acc[4][BSIZE];          // 8KB
    const int t = threadIdx.x;
    const int b = blockIdx.x;
    const int c = blockIdx.y;

    const uint32_t cnt  = min(gcursor[b], (uint32_t)REG);
    const uint32_t clen = (cnt + ACCH - 1) / ACCH;
    const uint32_t s0   = c * clen;
    const uint32_t s1   = min(cnt, s0 + clen);

    #pragma unroll
    for (int w = 0; w < 4; ++w) { acc[w][t] = 0.0f; acc[w][t + 256] = 0.0f; }
    __syncthreads();

    const int wave = t >> 6;
    const uint32_t* reg = pairs + (size_t)b * REG;
    for (uint32_t i = s0 + t; i < s1; i += STHREADS) {
        const uint32_t p = reg[i];
        atomicAdd(&acc[wave][p & NMASK], __uint_as_float(p & ~NMASK));
    }
    __syncthreads();

    float* dst = partial + (((size_t)b * ACCH + c) << BSHIFT);
    dst[t]       = acc[0][t] + acc[1][t] + acc[2][t] + acc[3][t];
    dst[t + 256] = acc[0][t + 256] + acc[1][t + 256] + acc[2][t + 256] + acc[3][t + 256];
}

// ---------------- K3: reduce ACCH chunk-partials -> out -----------------------
__global__ __launch_bounds__(STHREADS) void lj_reduce_kernel(
    const float* __restrict__ partial, float* __restrict__ out, int n_nodes)
{
    const int n = blockIdx.x * STHREADS + threadIdx.x;
    if (n < n_nodes) {
        const int b = n >> BSHIFT;
        const int i = n & (BSIZE - 1);
        float s = 0.0f;
        #pragma unroll
        for (int c = 0; c < ACCH; ++c)
            s += partial[(((size_t)b * ACCH + c) << BSHIFT) + i];
        out[n] = s;
    }
}

// ---------------- fallback: direct device-scope atomics -----------------------
__global__ __launch_bounds__(STHREADS) void lj_scatter_direct(
    const float* __restrict__ sigma,
    const float* __restrict__ delta,
    const float* __restrict__ epsilon,
    const float* __restrict__ edge_len,
    const float* __restrict__ edge_cutoff,
    const int*  __restrict__ edge_index,
    const int*  __restrict__ atom_types,
    float* __restrict__ out,
    int n_edges)
{
    __shared__ float s_sig[256], s_dlt[256], s_eps[256];
    const int t = threadIdx.x;
    load_params(sigma, delta, epsilon, s_sig, s_dlt, s_eps, t);
    __syncthreads();

    const int base = (blockIdx.x * STHREADS + t) * 4;
    if (base >= n_edges) return;
    const int lim = min(base + 4, n_edges);
    for (int e = base; e < lim; ++e) {
        const int ci = edge_index[e];
        const int oi = edge_index[n_edges + e];
        const int fl = (atom_types[ci] << 4) | atom_types[oi];
        const float en = lj_energy(s_sig[fl], s_dlt[fl], s_eps[fl],
                                   edge_len[e], edge_cutoff[e]);
        atomicAdd(out + ci, en);
    }
}

static inline size_t align16(size_t x) { return (x + 15) & ~(size_t)15; }

extern "C" void kernel_launch(void* const* d_in, const int* in_sizes, int n_in,
                              void* d_out, int out_size, void* d_ws, size_t ws_size,
                              hipStream_t stream) {
    const float* sigma       = (const float*)d_in[0];
    const float* delta       = (const float*)d_in[1];
    const float* epsilon     = (const float*)d_in[2];
    const float* edge_len    = (const float*)d_in[3];
    const float* edge_cutoff = (const float*)d_in[4];
    const int*   edge_index  = (const int*)d_in[5];
    const int*   atom_types  = (const int*)d_in[6];
    float*       out         = (float*)d_out;

    const int n_edges = in_sizes[3];
    const int n_nodes = in_sizes[6];

    const int nblk    = (n_edges + EPB - 1) / EPB;
    const int nbucket = (n_nodes + BSIZE - 1) / BSIZE;
    const int nwords  = (n_nodes + 7) >> 3;

    // region size: 2x mean bucket load (uniform edges -> 128 sigma of headroom)
    int REG = 2 * (n_edges / (nbucket > 0 ? nbucket : 1));
    REG = ((REG + 1023) / 1024) * 1024;
    if (REG < 2048) REG = 2048;

    const size_t gcur_bytes   = align16((size_t)MAXB2 * sizeof(uint32_t));
    const size_t packed_bytes = align16((size_t)nwords * sizeof(uint32_t));
    const size_t pairs_bytes  = align16((size_t)nbucket * REG * sizeof(uint32_t));
    const size_t part_bytes   = align16((size_t)nbucket * ACCH * BSIZE * sizeof(float));
    const size_t need = gcur_bytes + packed_bytes + pairs_bytes + part_bytes;

    if (nbucket <= MAXB2 && nwords <= LDSWORDS && ws_size >= need) {
        char* p = (char*)d_ws;
        uint32_t* gcursor = (uint32_t*)p;  p += gcur_bytes;
        uint32_t* packed  = (uint32_t*)p;  p += packed_bytes;
        uint32_t* pairs   = (uint32_t*)p;  p += pairs_bytes;
        float*    partial = (float*)p;

        const int pgrid = (nwords + STHREADS - 1) / STHREADS;
        pack_types_kernel<<<pgrid, STHREADS, 0, stream>>>(
            atom_types, packed, gcursor, n_nodes);

        lj_fused<<<nblk, THREADS, 0, stream>>>(
            sigma, delta, epsilon, edge_len, edge_cutoff,
            edge_index, packed, gcursor, pairs, n_edges, n_nodes, nbucket, REG);

        lj_accum_kernel<<<dim3(nbucket, ACCH), STHREADS, 0, stream>>>(
            pairs, gcursor, partial, REG);

        const int rgrid = (n_nodes + STHREADS - 1) / STHREADS;
        lj_reduce_kernel<<<rgrid, STHREADS, 0, stream>>>(partial, out, n_nodes);
    } else {
        hipMemsetAsync(d_out, 0, (size_t)out_size * sizeof(float), stream);
        const int grid = (n_edges + STHREADS * 4 - 1) / (STHREADS * 4);
        lj_scatter_direct<<<grid, STHREADS, 0, stream>>>(
            sigma, delta, epsilon, edge_len, edge_cutoff,
            edge_index, atom_types, out, n_edges);
    }
}